// Round 2
// baseline (1410.612 us; speedup 1.0000x reference)
//
#include <hip/hip_runtime.h>
#include <hip/hip_bf16.h>
#include <cstdint>

#define N_NODES 100000
#define N_EDGES 3200000
#define F_IN    512
#define F_HID   256
#define F_OUT   64
#define CAP     96   // max ELL slots/row; Poisson(32) max over 100K rows ~65, 96 is safe

// ---------------- ELL build ----------------

__global__ __launch_bounds__(256) void zero_cursors_kernel(int* __restrict__ cursor, int n) {
    int i = blockIdx.x * 256 + threadIdx.x;
    if (i < n) cursor[i] = 0;
}

__global__ __launch_bounds__(256) void ell_scatter_kernel(
    const int* __restrict__ rows, const int* __restrict__ cols,
    const float* __restrict__ vals, int* __restrict__ cursor,
    int* __restrict__ ell_col, float* __restrict__ ell_val, int e_count) {
    int e = blockIdx.x * 256 + threadIdx.x;
    if (e >= e_count) return;
    int r = rows[e];
    int p = atomicAdd(&cursor[r], 1);
    if (p < CAP) {
        ell_col[(size_t)r * CAP + p] = cols[e];
        ell_val[(size_t)r * CAP + p] = vals[e];
    }
}

// ---------------- fp32 register-tiled GEMM (no fp32 MFMA on CDNA4) ----------------
// BM=128, BN=64, BK=32; 256 threads; 8x4 accumulator per thread.

template<int BM, int BN, int BK>
__global__ __launch_bounds__(256) void gemm_f32_kernel(
    const float* __restrict__ A, const float* __restrict__ B,
    float* __restrict__ C, int M, int N, int K) {
    __shared__ float As[BK][BM + 4];  // +4 pad: conflict-free col reads, keeps 16B align
    __shared__ float Bs[BK][BN + 4];

    const int tid = threadIdx.x;
    const int tx = tid & 15;        // n-direction (4 cols each)
    const int ty = tid >> 4;        // m-direction (8 rows each)
    const int m0 = blockIdx.y * BM;
    const int n0 = blockIdx.x * BN;

    float acc[8][4] = {};

    const int arow = tid & 127;
    const int kg0  = tid >> 7;      // 0 or 1
    const int row  = m0 + arow;

    for (int k0 = 0; k0 < K; k0 += BK) {
        // A tile: 128 rows x 32 k -> stored transposed As[k][m]
        #pragma unroll
        for (int i = 0; i < 4; i++) {
            int kg = kg0 + 2 * i;   // covers kg 0..7 (float4 chunks of k)
            float4 v = make_float4(0.f, 0.f, 0.f, 0.f);
            if (row < M) v = *(const float4*)(A + (size_t)row * K + k0 + kg * 4);
            As[kg * 4 + 0][arow] = v.x;
            As[kg * 4 + 1][arow] = v.y;
            As[kg * 4 + 2][arow] = v.z;
            As[kg * 4 + 3][arow] = v.w;
        }
        // B tile: 32 k-rows x 64 cols
        #pragma unroll
        for (int i = 0; i < 2; i++) {
            int idx = tid + i * 256;
            int kr = idx >> 4, c4 = idx & 15;
            *(float4*)&Bs[kr][c4 * 4] =
                *(const float4*)(B + (size_t)(k0 + kr) * N + n0 + c4 * 4);
        }
        __syncthreads();

        #pragma unroll
        for (int kk = 0; kk < BK; kk++) {
            float4 a0 = *(const float4*)&As[kk][ty * 8];
            float4 a1 = *(const float4*)&As[kk][ty * 8 + 4];
            float4 b  = *(const float4*)&Bs[kk][tx * 4];
            float a[8] = {a0.x, a0.y, a0.z, a0.w, a1.x, a1.y, a1.z, a1.w};
            float bb[4] = {b.x, b.y, b.z, b.w};
            #pragma unroll
            for (int i = 0; i < 8; i++)
                #pragma unroll
                for (int j = 0; j < 4; j++)
                    acc[i][j] = fmaf(a[i], bb[j], acc[i][j]);
        }
        __syncthreads();
    }

    #pragma unroll
    for (int i = 0; i < 8; i++) {
        int m = m0 + ty * 8 + i;
        if (m < M) {
            float4 v = make_float4(acc[i][0], acc[i][1], acc[i][2], acc[i][3]);
            *(float4*)(C + (size_t)m * N + n0 + tx * 4) = v;
        }
    }
}

// ---------------- SpMM layer 1 (+ReLU), feature-split for L3 residency ----------------
// Pass processes features [f0, f0+128). Per-pass gather line-footprint of H0 is 51 MB
// (half the lines of each 1 KB row) -> stays resident in 256 MB Infinity Cache, vs the
// unsplit version whose 280 MB total stream footprint thrashed L3 (measured 1.61 GB fetch).
// Block = 256 threads = 2 rows x 128 features.

__global__ __launch_bounds__(256) void spmm_relu_half_kernel(
    const float* __restrict__ H0, const int* __restrict__ ell_col,
    const float* __restrict__ ell_val, const int* __restrict__ cursor,
    float* __restrict__ H1, int f0) {
    const int r = blockIdx.x * 2 + (threadIdx.x >> 7);
    const int t = (threadIdx.x & 127) + f0;
    int n = cursor[r]; if (n > CAP) n = CAP;
    const int*   cols = ell_col + (size_t)r * CAP;
    const float* vals = ell_val + (size_t)r * CAP;
    float acc = 0.f;
    int j = 0;
    for (; j + 4 <= n; j += 4) {   // 4 concurrent gathers for MLP
        int4   c = *(const int4*)(cols + j);
        float4 v = *(const float4*)(vals + j);
        float g0 = H0[(size_t)c.x * F_HID + t];
        float g1 = H0[(size_t)c.y * F_HID + t];
        float g2 = H0[(size_t)c.z * F_HID + t];
        float g3 = H0[(size_t)c.w * F_HID + t];
        acc = fmaf(v.x, g0, acc);
        acc = fmaf(v.y, g1, acc);
        acc = fmaf(v.z, g2, acc);
        acc = fmaf(v.w, g3, acc);
    }
    for (; j < n; j++)
        acc = fmaf(vals[j], H0[(size_t)cols[j] * F_HID + t], acc);
    H1[(size_t)r * F_HID + t] = fmaxf(acc, 0.f);
}

// ---------------- SpMM layer 2 + fused softmax: one wave (64 lanes = 64 classes) per row

__global__ __launch_bounds__(256) void spmm_softmax_kernel(
    const float* __restrict__ H2, const int* __restrict__ ell_col,
    const float* __restrict__ ell_val, const int* __restrict__ cursor,
    float* __restrict__ out) {
    const int lane = threadIdx.x & 63;
    const int r = blockIdx.x * 4 + (threadIdx.x >> 6);
    int n = cursor[r]; if (n > CAP) n = CAP;
    const int*   cols = ell_col + (size_t)r * CAP;
    const float* vals = ell_val + (size_t)r * CAP;
    float acc = 0.f;
    int j = 0;
    for (; j + 4 <= n; j += 4) {
        int4   c = *(const int4*)(cols + j);
        float4 v = *(const float4*)(vals + j);
        acc = fmaf(v.x, H2[(size_t)c.x * F_OUT + lane], acc);
        acc = fmaf(v.y, H2[(size_t)c.y * F_OUT + lane], acc);
        acc = fmaf(v.z, H2[(size_t)c.z * F_OUT + lane], acc);
        acc = fmaf(v.w, H2[(size_t)c.w * F_OUT + lane], acc);
    }
    for (; j < n; j++)
        acc = fmaf(vals[j], H2[(size_t)cols[j] * F_OUT + lane], acc);

    // softmax across the wave (64 classes)
    float m = acc;
    #pragma unroll
    for (int o = 32; o >= 1; o >>= 1) m = fmaxf(m, __shfl_xor(m, o, 64));
    float e = expf(acc - m);
    float s = e;
    #pragma unroll
    for (int o = 32; o >= 1; o >>= 1) s += __shfl_xor(s, o, 64);
    out[(size_t)r * F_OUT + lane] = e / s;
}

// ---------------- launcher ----------------

extern "C" void kernel_launch(void* const* d_in, const int* in_sizes, int n_in,
                              void* d_out, int out_size, void* d_ws, size_t ws_size,
                              hipStream_t stream) {
    const float* X     = (const float*)d_in[0];
    const int*   erows = (const int*)  d_in[1];
    const int*   ecols = (const int*)  d_in[2];
    const float* evals = (const float*)d_in[3];
    const float* W0    = (const float*)d_in[4];
    const float* W1    = (const float*)d_in[5];
    float* out = (float*)d_out;

    // workspace layout (ws poisoned 0xAA each call; cursors zeroed in-kernel)
    char* ws = (char*)d_ws;
    float* H0 = (float*)ws;                                        // 102.4 MB
    float* H1 = (float*)(ws + (size_t)N_NODES * F_HID * 4);        // 102.4 MB
    char*  p  = ws + 2 * (size_t)N_NODES * F_HID * 4;
    int*   cursor  = (int*)p;   p += (size_t)N_NODES * 4;          // 0.4 MB (16B-aligned after)
    int*   ell_col = (int*)p;   p += (size_t)N_NODES * CAP * 4;    // 38.4 MB
    float* ell_val = (float*)p;                                    // 38.4 MB
    float* H2 = H0;  // H0 dead after spmm_relu; reuse for H2 (N*64)

    zero_cursors_kernel<<<(N_NODES + 255) / 256, 256, 0, stream>>>(cursor, N_NODES);
    ell_scatter_kernel<<<(N_EDGES + 255) / 256, 256, 0, stream>>>(
        erows, ecols, evals, cursor, ell_col, ell_val, N_EDGES);

    // H0 = X @ W0   [100000,512] x [512,256]
    gemm_f32_kernel<128, 64, 32><<<dim3(F_HID / 64, (N_NODES + 127) / 128), 256, 0, stream>>>(
        X, W0, H0, N_NODES, F_HID, F_IN);

    // H1 = relu(A @ H0), two feature-split passes for L3 residency
    spmm_relu_half_kernel<<<N_NODES / 2, 256, 0, stream>>>(H0, ell_col, ell_val, cursor, H1, 0);
    spmm_relu_half_kernel<<<N_NODES / 2, 256, 0, stream>>>(H0, ell_col, ell_val, cursor, H1, 128);

    // H2 = H1 @ W1  [100000,256] x [256,64]
    gemm_f32_kernel<128, 64, 32><<<dim3(F_OUT / 64, (N_NODES + 127) / 128), 256, 0, stream>>>(
        H1, W1, H2, N_NODES, F_OUT, F_HID);

    // out = softmax(A @ H2)
    spmm_softmax_kernel<<<N_NODES / 4, 256, 0, stream>>>(H2, ell_col, ell_val, cursor, out);
}

// Round 3
// 989.706 us; speedup vs baseline: 1.4253x; 1.4253x over previous
//
#include <hip/hip_runtime.h>
#include <hip/hip_bf16.h>
#include <hip/hip_fp16.h>
#include <cstdint>

#define N_NODES 100000
#define N_EDGES 3200000
#define F_IN    512
#define F_HID   256
#define F_OUT   64
#define CAP     96   // max ELL slots/row; Poisson(32) max over 100K rows ~65, 96 is safe

typedef _Float16 half8_t __attribute__((ext_vector_type(8)));
typedef _Float16 half4_t __attribute__((ext_vector_type(4)));
typedef float    float4_t __attribute__((ext_vector_type(4)));

// ---------------- ELL build ----------------

__global__ __launch_bounds__(256) void zero_cursors_kernel(int* __restrict__ cursor, int n) {
    int i = blockIdx.x * 256 + threadIdx.x;
    if (i < n) cursor[i] = 0;
}

__global__ __launch_bounds__(256) void ell_scatter_kernel(
    const int* __restrict__ rows, const int* __restrict__ cols,
    const float* __restrict__ vals, int* __restrict__ cursor,
    int* __restrict__ ell_col, float* __restrict__ ell_val, int e_count) {
    int e = blockIdx.x * 256 + threadIdx.x;
    if (e >= e_count) return;
    int r = rows[e];
    int p = atomicAdd(&cursor[r], 1);
    if (p < CAP) {
        ell_col[(size_t)r * CAP + p] = cols[e];
        ell_val[(size_t)r * CAP + p] = vals[e];
    }
}

// ---------------- weight preconvert: W0 -> W0T fp16 [N][K], W1 -> W1T fp16 [N][K] ----

__global__ __launch_bounds__(256) void convert_w_kernel(
    const float* __restrict__ W0, const float* __restrict__ W1,
    _Float16* __restrict__ W0T, _Float16* __restrict__ W1T) {
    int i = blockIdx.x * 256 + threadIdx.x;
    if (i < F_HID * F_IN) {                 // W0T[n][k] = W0[k][n], 256x512
        int n = i >> 9, k = i & 511;
        W0T[i] = (_Float16)W0[k * F_HID + n];
    }
    int j = i - F_HID * F_IN;
    if (j >= 0 && j < F_OUT * F_HID) {      // W1T[n][k] = W1[k][n], 64x256
        int n = j >> 8, k = j & 255;
        W1T[j] = (_Float16)W1[k * F_OUT + n];
    }
}

// ---------------- GEMM1: H0[M,256] = X[M,512] @ W0, fp16 MFMA, LDS-free ----------------
// Block = 256 threads = 4 waves. Block covers 64 m-rows x all 256 n (X read ONCE from HBM).
// Wave w covers n in [64w, 64w+64): 4x4 tiles of 16x16, K-step 32.
// Layouts (guide-verified): A[m=lane&15][k=quad*8+j]; B[k=quad*8+j][n=lane&15];
// D: col(n)=lane&15, row(m)=quad*4+reg.

__global__ __launch_bounds__(256) void gemm1_mfma_kernel(
    const float* __restrict__ X, const _Float16* __restrict__ W0T,
    _Float16* __restrict__ H0) {
    const int wave = threadIdx.x >> 6;
    const int lane = threadIdx.x & 63;
    const int l15  = lane & 15;
    const int quad = lane >> 4;
    const int m0   = blockIdx.x * 64;
    const int n0   = wave * 64;

    float4_t acc[4][4] = {};   // [mt][nt]

    int row[4];
    #pragma unroll
    for (int mt = 0; mt < 4; mt++) {
        int r = m0 + mt * 16 + l15;
        row[mt] = r < N_NODES ? r : N_NODES - 1;  // clamp: garbage rows never stored
    }

    for (int k0 = 0; k0 < F_IN; k0 += 32) {
        const int kk = k0 + quad * 8;
        half8_t b[4];
        #pragma unroll
        for (int nt = 0; nt < 4; nt++)
            b[nt] = *(const half8_t*)(W0T + (size_t)(n0 + nt * 16 + l15) * F_IN + kk);

        half8_t a[4];
        #pragma unroll
        for (int mt = 0; mt < 4; mt++) {
            const float* p = X + (size_t)row[mt] * F_IN + kk;
            float4_t lo = *(const float4_t*)p;
            float4_t hi = *(const float4_t*)(p + 4);
            half8_t f;
            f[0] = (_Float16)lo[0]; f[1] = (_Float16)lo[1];
            f[2] = (_Float16)lo[2]; f[3] = (_Float16)lo[3];
            f[4] = (_Float16)hi[0]; f[5] = (_Float16)hi[1];
            f[6] = (_Float16)hi[2]; f[7] = (_Float16)hi[3];
            a[mt] = f;
        }

        #pragma unroll
        for (int mt = 0; mt < 4; mt++)
            #pragma unroll
            for (int nt = 0; nt < 4; nt++)
                acc[mt][nt] = __builtin_amdgcn_mfma_f32_16x16x32_f16(
                    a[mt], b[nt], acc[mt][nt], 0, 0, 0);
    }

    #pragma unroll
    for (int mt = 0; mt < 4; mt++)
        #pragma unroll
        for (int reg = 0; reg < 4; reg++) {
            int m = m0 + mt * 16 + quad * 4 + reg;
            if (m < N_NODES) {
                #pragma unroll
                for (int nt = 0; nt < 4; nt++)
                    H0[(size_t)m * F_HID + n0 + nt * 16 + l15] =
                        (_Float16)acc[mt][nt][reg];
            }
        }
}

// ---------------- GEMM2: H2[M,64] = H1[M,256] @ W1, fp16 MFMA ----------------
// Block = 4 waves, each wave one 16-row m-tile x all 64 n (4 n-tiles). K=256 -> 8 steps.

__global__ __launch_bounds__(256) void gemm2_mfma_kernel(
    const _Float16* __restrict__ H1, const _Float16* __restrict__ W1T,
    _Float16* __restrict__ H2) {
    const int wave = threadIdx.x >> 6;
    const int lane = threadIdx.x & 63;
    const int l15  = lane & 15;
    const int quad = lane >> 4;
    const int m0   = blockIdx.x * 64 + wave * 16;

    int r = m0 + l15;
    if (r >= N_NODES) r = N_NODES - 1;

    float4_t acc[4] = {};

    for (int k0 = 0; k0 < F_HID; k0 += 32) {
        const int kk = k0 + quad * 8;
        half8_t a = *(const half8_t*)(H1 + (size_t)r * F_HID + kk);
        #pragma unroll
        for (int nt = 0; nt < 4; nt++) {
            half8_t b = *(const half8_t*)(W1T + (size_t)(nt * 16 + l15) * F_HID + kk);
            acc[nt] = __builtin_amdgcn_mfma_f32_16x16x32_f16(a, b, acc[nt], 0, 0, 0);
        }
    }

    #pragma unroll
    for (int reg = 0; reg < 4; reg++) {
        int m = m0 + quad * 4 + reg;
        if (m < N_NODES) {
            #pragma unroll
            for (int nt = 0; nt < 4; nt++)
                H2[(size_t)m * F_OUT + nt * 16 + l15] = (_Float16)acc[nt][reg];
        }
    }
}

// ---------------- SpMM layer 1 (+ReLU), fp16 gather ----------------
// Wave per row; lane t handles feats [4t,4t+4) -> one 8B load reads the WHOLE 512B
// neighbor row per wave per edge. fp32 accumulate, fp16 H1 out.

__global__ __launch_bounds__(256) void spmm_relu_kernel(
    const _Float16* __restrict__ H0, const int* __restrict__ ell_col,
    const float* __restrict__ ell_val, const int* __restrict__ cursor,
    _Float16* __restrict__ H1) {
    const int r = blockIdx.x * 4 + (threadIdx.x >> 6);
    const int t = threadIdx.x & 63;
    int n = cursor[r]; if (n > CAP) n = CAP;
    const int*   cols = ell_col + (size_t)r * CAP;
    const float* vals = ell_val + (size_t)r * CAP;
    const half4_t* H0v = (const half4_t*)H0;   // unit = 4 feats

    float4_t acc = {};
    int j = 0;
    for (; j + 4 <= n; j += 4) {
        int4   c = *(const int4*)(cols + j);
        float4 v = *(const float4*)(vals + j);
        half4_t g0 = H0v[(size_t)c.x * 64 + t];
        half4_t g1 = H0v[(size_t)c.y * 64 + t];
        half4_t g2 = H0v[(size_t)c.z * 64 + t];
        half4_t g3 = H0v[(size_t)c.w * 64 + t];
        #pragma unroll
        for (int i = 0; i < 4; i++) {
            acc[i] = fmaf(v.x, (float)g0[i], acc[i]);
            acc[i] = fmaf(v.y, (float)g1[i], acc[i]);
            acc[i] = fmaf(v.z, (float)g2[i], acc[i]);
            acc[i] = fmaf(v.w, (float)g3[i], acc[i]);
        }
    }
    for (; j < n; j++) {
        half4_t g = H0v[(size_t)cols[j] * 64 + t];
        float vv = vals[j];
        #pragma unroll
        for (int i = 0; i < 4; i++) acc[i] = fmaf(vv, (float)g[i], acc[i]);
    }
    half4_t o;
    #pragma unroll
    for (int i = 0; i < 4; i++) o[i] = (_Float16)fmaxf(acc[i], 0.f);
    ((half4_t*)H1)[(size_t)r * 64 + t] = o;
}

// ---------------- SpMM layer 2 + fused softmax, fp16 gather ----------------
// Wave per row, lane = class (64). fp32 softmax, fp32 out.

__global__ __launch_bounds__(256) void spmm_softmax_kernel(
    const _Float16* __restrict__ H2, const int* __restrict__ ell_col,
    const float* __restrict__ ell_val, const int* __restrict__ cursor,
    float* __restrict__ out) {
    const int lane = threadIdx.x & 63;
    const int r = blockIdx.x * 4 + (threadIdx.x >> 6);
    int n = cursor[r]; if (n > CAP) n = CAP;
    const int*   cols = ell_col + (size_t)r * CAP;
    const float* vals = ell_val + (size_t)r * CAP;
    float acc = 0.f;
    int j = 0;
    for (; j + 4 <= n; j += 4) {
        int4   c = *(const int4*)(cols + j);
        float4 v = *(const float4*)(vals + j);
        acc = fmaf(v.x, (float)H2[(size_t)c.x * F_OUT + lane], acc);
        acc = fmaf(v.y, (float)H2[(size_t)c.y * F_OUT + lane], acc);
        acc = fmaf(v.z, (float)H2[(size_t)c.z * F_OUT + lane], acc);
        acc = fmaf(v.w, (float)H2[(size_t)c.w * F_OUT + lane], acc);
    }
    for (; j < n; j++)
        acc = fmaf(vals[j], (float)H2[(size_t)cols[j] * F_OUT + lane], acc);

    float m = acc;
    #pragma unroll
    for (int o = 32; o >= 1; o >>= 1) m = fmaxf(m, __shfl_xor(m, o, 64));
    float e = expf(acc - m);
    float s = e;
    #pragma unroll
    for (int o = 32; o >= 1; o >>= 1) s += __shfl_xor(s, o, 64);
    out[(size_t)r * F_OUT + lane] = e / s;
}

// ---------------- launcher ----------------

extern "C" void kernel_launch(void* const* d_in, const int* in_sizes, int n_in,
                              void* d_out, int out_size, void* d_ws, size_t ws_size,
                              hipStream_t stream) {
    const float* X     = (const float*)d_in[0];
    const int*   erows = (const int*)  d_in[1];
    const int*   ecols = (const int*)  d_in[2];
    const float* evals = (const float*)d_in[3];
    const float* W0    = (const float*)d_in[4];
    const float* W1    = (const float*)d_in[5];
    float* out = (float*)d_out;

    // workspace layout (all regions 16B-aligned)
    char* p = (char*)d_ws;
    _Float16* H0  = (_Float16*)p; p += (size_t)N_NODES * F_HID * 2;   // 51.2 MB
    _Float16* H1  = (_Float16*)p; p += (size_t)N_NODES * F_HID * 2;   // 51.2 MB
    _Float16* H2  = (_Float16*)p; p += (size_t)N_NODES * F_OUT * 2;   // 12.8 MB
    _Float16* W0T = (_Float16*)p; p += (size_t)F_HID * F_IN * 2;      // 256 KB
    _Float16* W1T = (_Float16*)p; p += (size_t)F_OUT * F_HID * 2;     // 32 KB
    int*   cursor  = (int*)p;     p += (size_t)N_NODES * 4;           // 0.4 MB
    int*   ell_col = (int*)p;     p += (size_t)N_NODES * CAP * 4;     // 38.4 MB
    float* ell_val = (float*)p;                                       // 38.4 MB

    zero_cursors_kernel<<<(N_NODES + 255) / 256, 256, 0, stream>>>(cursor, N_NODES);
    ell_scatter_kernel<<<(N_EDGES + 255) / 256, 256, 0, stream>>>(
        erows, ecols, evals, cursor, ell_col, ell_val, N_EDGES);
    convert_w_kernel<<<(F_HID * F_IN + F_OUT * F_HID + 255) / 256, 256, 0, stream>>>(
        W0, W1, W0T, W1T);

    // H0 = fp16(X @ W0)
    gemm1_mfma_kernel<<<(N_NODES + 63) / 64, 256, 0, stream>>>(X, W0T, H0);

    // H1 = fp16(relu(A @ H0))
    spmm_relu_kernel<<<N_NODES / 4, 256, 0, stream>>>(H0, ell_col, ell_val, cursor, H1);

    // H2 = fp16(H1 @ W1)
    gemm2_mfma_kernel<<<(N_NODES + 63) / 64, 256, 0, stream>>>(H1, W1T, H2);

    // out = softmax(A @ H2)
    spmm_softmax_kernel<<<N_NODES / 4, 256, 0, stream>>>(H2, ell_col, ell_val, cursor, out);
}